// Round 1
// baseline (508.862 us; speedup 1.0000x reference)
//
#include <hip/hip_runtime.h>
#include <hip/hip_bf16.h>
#include <math.h>

#define N_TOK 8192
#define HDIM  1024
#define NE    8
#define TILE  128
#define BK    32
#define LDA   40   // padded bf16 leading dim for 32-wide K slab (breaks pow-2 bank stride)

typedef __attribute__((ext_vector_type(8))) short bf16x8;
typedef __attribute__((ext_vector_type(4))) float f32x4;

__device__ __forceinline__ short f2bf(float f) {
    union { float f; unsigned u; } v; v.f = f;
    unsigned r = v.u + 0x7FFFu + ((v.u >> 16) & 1u);   // round-to-nearest-even
    return (short)(r >> 16);
}

// ---------------- gating: fp32 logits, softmax, top-2, compact per-expert lists ---------------
__global__ __launch_bounds__(256)
void gate_topk_kernel(const float* __restrict__ x,
                      const float* __restrict__ gate_w,
                      const float* __restrict__ gate_b,
                      int* __restrict__ counts,
                      int* __restrict__ tok_list,    // [NE][N_TOK]
                      float* __restrict__ gate_list) // [NE][N_TOK]
{
    int t = blockIdx.x;
    const float* xt = x + (size_t)t * HDIM;
    float acc[NE];
#pragma unroll
    for (int e = 0; e < NE; ++e) acc[e] = 0.f;
    for (int k = threadIdx.x; k < HDIM; k += 256) {
        float xv = xt[k];
#pragma unroll
        for (int e = 0; e < NE; ++e) acc[e] += xv * gate_w[e * HDIM + k];
    }
#pragma unroll
    for (int e = 0; e < NE; ++e)
        for (int off = 32; off > 0; off >>= 1)
            acc[e] += __shfl_down(acc[e], off);

    __shared__ float lred[4][NE];
    int wave = threadIdx.x >> 6;
    int lane = threadIdx.x & 63;
    if (lane == 0) {
#pragma unroll
        for (int e = 0; e < NE; ++e) lred[wave][e] = acc[e];
    }
    __syncthreads();
    if (threadIdx.x == 0) {
        float logit[NE];
        float mx = -1e30f;
#pragma unroll
        for (int e = 0; e < NE; ++e) {
            logit[e] = lred[0][e] + lred[1][e] + lred[2][e] + lred[3][e] + gate_b[e];
            mx = fmaxf(mx, logit[e]);
        }
        float p[NE];
        float s = 0.f;
#pragma unroll
        for (int e = 0; e < NE; ++e) { p[e] = expf(logit[e] - mx); s += p[e]; }
        float inv = 1.f / s;
        // top-2 (strict > keeps lowest index on ties, matching lax.top_k)
        int i0 = 0;
#pragma unroll
        for (int e = 1; e < NE; ++e) if (logit[e] > logit[i0]) i0 = e;
        int i1 = (i0 == 0) ? 1 : 0;
#pragma unroll
        for (int e = 0; e < NE; ++e) if (e != i0 && logit[e] > logit[i1]) i1 = e;

        int p0 = atomicAdd(&counts[i0], 1);
        tok_list[i0 * N_TOK + p0]  = t;
        gate_list[i0 * N_TOK + p0] = p[i0] * inv;
        int p1 = atomicAdd(&counts[i1], 1);
        tok_list[i1 * N_TOK + p1]  = t;
        gate_list[i1 * N_TOK + p1] = p[i1] * inv;
    }
}

// ---------------- grouped per-expert GEMM: Y = gather(X) @ W_e^T, scatter-add with gate ------
__global__ __launch_bounds__(256)
void moe_gemm_kernel(const float* __restrict__ x,
                     const float* __restrict__ expert_w,
                     const float* __restrict__ expert_b,
                     const int* __restrict__ counts,
                     const int* __restrict__ tok_list,
                     const float* __restrict__ gate_list,
                     float* __restrict__ out)
{
    int e   = blockIdx.z;
    int cnt = counts[e];
    int m0  = blockIdx.x * TILE;
    if (m0 >= cnt) return;
    int n0  = blockIdx.y * TILE;

    __shared__ __align__(16) short As[TILE * LDA];
    __shared__ __align__(16) short Bs[TILE * LDA];

    int tid = threadIdx.x;
    int row = tid >> 1;          // 0..127: one staging row per 2 threads
    int kb  = (tid & 1) * 16;    // first/second 16 K-elements

    int tokRow = -1;
    if (m0 + row < cnt) tokRow = tok_list[e * N_TOK + m0 + row];
    const float* aSrc = (tokRow >= 0) ? (x + (size_t)tokRow * HDIM + kb) : nullptr;
    const float* bSrc = expert_w + ((size_t)e * HDIM + (size_t)(n0 + row)) * HDIM + kb;

    int wave = tid >> 6, lane = tid & 63;
    int wm = (wave >> 1) * 64, wn = (wave & 1) * 64;   // 2x2 waves, 64x64 each
    int lrow = lane & 15, quad = lane >> 4;

    f32x4 acc[4][4];
#pragma unroll
    for (int mi = 0; mi < 4; ++mi)
#pragma unroll
        for (int ni = 0; ni < 4; ++ni)
            acc[mi][ni] = (f32x4){0.f, 0.f, 0.f, 0.f};

    for (int k0 = 0; k0 < HDIM; k0 += BK) {
        {   // stage A (gathered tokens), fp32 -> bf16
            short* dst = As + row * LDA + kb;
            if (aSrc) {
                const float4* src = (const float4*)(aSrc + k0);
#pragma unroll
                for (int i = 0; i < 4; ++i) {
                    float4 v = src[i];
                    dst[i * 4 + 0] = f2bf(v.x);
                    dst[i * 4 + 1] = f2bf(v.y);
                    dst[i * 4 + 2] = f2bf(v.z);
                    dst[i * 4 + 3] = f2bf(v.w);
                }
            } else {
#pragma unroll
                for (int i = 0; i < 16; ++i) dst[i] = 0;
            }
        }
        {   // stage B (expert weights, [out][in] K-contiguous)
            short* dst = Bs + row * LDA + kb;
            const float4* src = (const float4*)(bSrc + k0);
#pragma unroll
            for (int i = 0; i < 4; ++i) {
                float4 v = src[i];
                dst[i * 4 + 0] = f2bf(v.x);
                dst[i * 4 + 1] = f2bf(v.y);
                dst[i * 4 + 2] = f2bf(v.z);
                dst[i * 4 + 3] = f2bf(v.w);
            }
        }
        __syncthreads();

        bf16x8 af[4], bfr[4];
#pragma unroll
        for (int i = 0; i < 4; ++i) {
            af[i]  = *(const bf16x8*)(As + (wm + i * 16 + lrow) * LDA + quad * 8);
            bfr[i] = *(const bf16x8*)(Bs + (wn + i * 16 + lrow) * LDA + quad * 8);
        }
#pragma unroll
        for (int mi = 0; mi < 4; ++mi)
#pragma unroll
            for (int ni = 0; ni < 4; ++ni)
                acc[mi][ni] = __builtin_amdgcn_mfma_f32_16x16x32_bf16(
                    af[mi], bfr[ni], acc[mi][ni], 0, 0, 0);
        __syncthreads();
    }

    // epilogue: bias + gate scale + scatter-add
#pragma unroll
    for (int mi = 0; mi < 4; ++mi) {
#pragma unroll
        for (int r = 0; r < 4; ++r) {
            int listRow = m0 + wm + mi * 16 + quad * 4 + r;
            if (listRow < cnt) {
                int   token = tok_list[e * N_TOK + listRow];
                float g     = gate_list[e * N_TOK + listRow];
                float* orow = out + (size_t)token * HDIM;
#pragma unroll
                for (int ni = 0; ni < 4; ++ni) {
                    int col = n0 + wn + ni * 16 + lrow;
                    float val = (acc[mi][ni][r] + expert_b[e * HDIM + col]) * g;
                    atomicAdd(orow + col, val);
                }
            }
        }
    }
}

extern "C" void kernel_launch(void* const* d_in, const int* in_sizes, int n_in,
                              void* d_out, int out_size, void* d_ws, size_t ws_size,
                              hipStream_t stream)
{
    const float* x        = (const float*)d_in[0];
    const float* gate_w   = (const float*)d_in[1];
    const float* gate_b   = (const float*)d_in[2];
    const float* expert_w = (const float*)d_in[3];
    const float* expert_b = (const float*)d_in[4];
    float* out = (float*)d_out;

    char* ws = (char*)d_ws;
    int*   counts    = (int*)ws;                                    // 256 B
    int*   tok_list  = (int*)(ws + 256);                            // NE*N_TOK*4 = 256 KB
    float* gate_list = (float*)(ws + 256 + NE * N_TOK * 4);         // 256 KB

    hipMemsetAsync(counts, 0, 256, stream);
    hipMemsetAsync(d_out, 0, (size_t)out_size * sizeof(float), stream);

    gate_topk_kernel<<<N_TOK, 256, 0, stream>>>(x, gate_w, gate_b,
                                                counts, tok_list, gate_list);

    dim3 grid(N_TOK / TILE, HDIM / TILE, NE);   // 64 x 8 x 8, empty tiles early-exit
    moe_gemm_kernel<<<grid, 256, 0, stream>>>(x, expert_w, expert_b,
                                              counts, tok_list, gate_list, out);
}

// Round 2
// 505.357 us; speedup vs baseline: 1.0069x; 1.0069x over previous
//
#include <hip/hip_runtime.h>
#include <hip/hip_bf16.h>
#include <math.h>

#define N_TOK 8192
#define HDIM  1024
#define NE    8
#define TILE  128
#define BK    32

typedef __attribute__((ext_vector_type(8))) short bf16x8;
typedef __attribute__((ext_vector_type(4))) float f32x4;
typedef unsigned short u16;

__device__ __forceinline__ u16 f2bf(float f) {
    union { float f; unsigned u; } v; v.f = f;
    unsigned r = v.u + 0x7FFFu + ((v.u >> 16) & 1u);   // round-to-nearest-even
    return (u16)(r >> 16);
}

__device__ __forceinline__ void gld_lds16(const void* g, void* lds) {
    __builtin_amdgcn_global_load_lds(
        (const __attribute__((address_space(1))) unsigned int*)g,
        (__attribute__((address_space(3))) unsigned int*)lds,
        16, 0, 0);
}

// ---------------- expert_w fp32 -> bf16 (one pass, 8M elems) ----------------
__global__ __launch_bounds__(256)
void convert_w_kernel(const float* __restrict__ w, u16* __restrict__ wbf) {
    size_t i = (size_t)blockIdx.x * 256 + threadIdx.x;   // float4 index
    float4 v = ((const float4*)w)[i];
    ushort4 b;
    b.x = f2bf(v.x); b.y = f2bf(v.y); b.z = f2bf(v.z); b.w = f2bf(v.w);
    ((ushort4*)wbf)[i] = b;
}

// ---- gating (wave per token): logits fp32, softmax, top-2, compact lists; also x -> bf16 ----
__global__ __launch_bounds__(256)
void gate_topk_kernel(const float* __restrict__ x,
                      const float* __restrict__ gate_w,
                      const float* __restrict__ gate_b,
                      u16* __restrict__ xbf,
                      int* __restrict__ counts,
                      int* __restrict__ tok_list,    // [NE][N_TOK]
                      float* __restrict__ gate_list) // [NE][N_TOK]
{
    int wave = threadIdx.x >> 6, lane = threadIdx.x & 63;
    int t = blockIdx.x * 4 + wave;
    const float4* xt = (const float4*)(x + (size_t)t * HDIM);
    ushort4* xb = (ushort4*)(xbf + (size_t)t * HDIM);

    float acc[NE];
#pragma unroll
    for (int e = 0; e < NE; ++e) acc[e] = 0.f;

#pragma unroll
    for (int i = 0; i < 4; ++i) {
        int f = i * 64 + lane;            // float4 index within row
        float4 v = xt[f];
        ushort4 b;
        b.x = f2bf(v.x); b.y = f2bf(v.y); b.z = f2bf(v.z); b.w = f2bf(v.w);
        xb[f] = b;
#pragma unroll
        for (int e = 0; e < NE; ++e) {
            float4 wv = ((const float4*)(gate_w + e * HDIM))[f];
            acc[e] += v.x * wv.x + v.y * wv.y + v.z * wv.z + v.w * wv.w;
        }
    }
#pragma unroll
    for (int e = 0; e < NE; ++e)
        for (int off = 32; off > 0; off >>= 1)
            acc[e] += __shfl_down(acc[e], off);

    if (lane == 0) {
        float logit[NE];
        float mx = -1e30f;
#pragma unroll
        for (int e = 0; e < NE; ++e) {
            logit[e] = acc[e] + gate_b[e];
            mx = fmaxf(mx, logit[e]);
        }
        float p[NE], s = 0.f;
#pragma unroll
        for (int e = 0; e < NE; ++e) { p[e] = expf(logit[e] - mx); s += p[e]; }
        float inv = 1.f / s;
        int i0 = 0;
#pragma unroll
        for (int e = 1; e < NE; ++e) if (logit[e] > logit[i0]) i0 = e;
        int i1 = (i0 == 0) ? 1 : 0;
#pragma unroll
        for (int e = 0; e < NE; ++e) if (e != i0 && logit[e] > logit[i1]) i1 = e;

        int p0 = atomicAdd(&counts[i0], 1);
        tok_list[i0 * N_TOK + p0]  = t;
        gate_list[i0 * N_TOK + p0] = p[i0] * inv;
        int p1 = atomicAdd(&counts[i1], 1);
        tok_list[i1 * N_TOK + p1]  = t;
        gate_list[i1 * N_TOK + p1] = p[i1] * inv;
    }
}

// ---- grouped per-expert GEMM (bf16, async LDS staging): Y = gather(X) @ W_e^T, scatter-add ----
// LDS layout: chunk-major [4][128] slots of 16B (8 bf16). Matches global_load_lds's
// wave-uniform-base + lane*16 write rule AND gives conflict-free ds_read_b128 fragments.
__global__ __launch_bounds__(256)
void moe_gemm_kernel(const u16* __restrict__ xbf,
                     const u16* __restrict__ wbf,
                     const float* __restrict__ expert_b,
                     const int* __restrict__ counts,
                     const int* __restrict__ tok_list,
                     const float* __restrict__ gate_list,
                     float* __restrict__ out)
{
    int e   = blockIdx.z;
    int cnt = counts[e];
    int m0  = blockIdx.x * TILE;
    if (m0 >= cnt) return;
    int n0  = blockIdx.y * TILE;

    __shared__ __align__(16) u16 As[4 * 128 * 8];   // 8 KB
    __shared__ __align__(16) u16 Bs[4 * 128 * 8];   // 8 KB

    int tid = threadIdx.x;
    int w = tid >> 6, l = tid & 63;
    // staging assignment: slot s = w*64 + l (instr0), s+256 (instr1); chunk = s>>7, row = s&127
    int r  = ((w & 1) << 6) + l;     // row this lane stages (both instrs: same row)
    int c0 = w >> 1;                 // chunk for instr0 (instr1 = c0+2)

    int tr = m0 + r; if (tr > cnt - 1) tr = cnt - 1;      // clamp: dup rows discarded in epilogue
    int tokA = tok_list[e * N_TOK + tr];
    const u16* aptr = xbf + (size_t)tokA * HDIM + c0 * 8;
    const u16* bptr = wbf + (size_t)(e * HDIM + n0 + r) * HDIM + c0 * 8;

    u16* ldsA0 = As + (w * 64) * 8;
    u16* ldsA1 = As + (256 + w * 64) * 8;
    u16* ldsB0 = Bs + (w * 64) * 8;
    u16* ldsB1 = Bs + (256 + w * 64) * 8;

    int wm = (w >> 1) * 64, wn = (w & 1) * 64;   // 2x2 waves, 64x64 each
    int lrow = l & 15, quad = l >> 4;

    f32x4 acc[4][4];
#pragma unroll
    for (int mi = 0; mi < 4; ++mi)
#pragma unroll
        for (int ni = 0; ni < 4; ++ni)
            acc[mi][ni] = (f32x4){0.f, 0.f, 0.f, 0.f};

    for (int k0 = 0; k0 < HDIM; k0 += BK) {
        gld_lds16(aptr + k0,      ldsA0);
        gld_lds16(aptr + k0 + 16, ldsA1);
        gld_lds16(bptr + k0,      ldsB0);
        gld_lds16(bptr + k0 + 16, ldsB1);
        __syncthreads();

        bf16x8 af[4], bfr[4];
#pragma unroll
        for (int i = 0; i < 4; ++i) {
            af[i]  = *(const bf16x8*)(As + (quad * 128 + wm + i * 16 + lrow) * 8);
            bfr[i] = *(const bf16x8*)(Bs + (quad * 128 + wn + i * 16 + lrow) * 8);
        }
#pragma unroll
        for (int mi = 0; mi < 4; ++mi)
#pragma unroll
            for (int ni = 0; ni < 4; ++ni)
                acc[mi][ni] = __builtin_amdgcn_mfma_f32_16x16x32_bf16(
                    af[mi], bfr[ni], acc[mi][ni], 0, 0, 0);
        __syncthreads();
    }

    // epilogue: bias + gate scale + scatter-add (C/D: col=lane&15, row=quad*4+reg)
#pragma unroll
    for (int mi = 0; mi < 4; ++mi) {
#pragma unroll
        for (int rr = 0; rr < 4; ++rr) {
            int listRow = m0 + wm + mi * 16 + quad * 4 + rr;
            if (listRow < cnt) {
                int   token = tok_list[e * N_TOK + listRow];
                float g     = gate_list[e * N_TOK + listRow];
                float* orow = out + (size_t)token * HDIM;
#pragma unroll
                for (int ni = 0; ni < 4; ++ni) {
                    int col = n0 + wn + ni * 16 + lrow;
                    float val = (acc[mi][ni][rr] + expert_b[e * HDIM + col]) * g;
                    atomicAdd(orow + col, val);
                }
            }
        }
    }
}

extern "C" void kernel_launch(void* const* d_in, const int* in_sizes, int n_in,
                              void* d_out, int out_size, void* d_ws, size_t ws_size,
                              hipStream_t stream)
{
    const float* x        = (const float*)d_in[0];
    const float* gate_w   = (const float*)d_in[1];
    const float* gate_b   = (const float*)d_in[2];
    const float* expert_w = (const float*)d_in[3];
    const float* expert_b = (const float*)d_in[4];
    float* out = (float*)d_out;

    char* ws = (char*)d_ws;
    int*   counts    = (int*)ws;                                   // 256 B (pad to 1 KB)
    int*   tok_list  = (int*)(ws + 1024);                          // 256 KB
    float* gate_list = (float*)(ws + 1024 + NE * N_TOK * 4);       // 256 KB
    u16*   xbf       = (u16*)(ws + 1024 + 2 * NE * N_TOK * 4);     // 16 MB
    u16*   wbf       = xbf + (size_t)N_TOK * HDIM;                 // 16 MB

    hipMemsetAsync(counts, 0, 256, stream);
    hipMemsetAsync(d_out, 0, (size_t)out_size * sizeof(float), stream);

    convert_w_kernel<<<(NE * HDIM * HDIM / 4) / 256, 256, 0, stream>>>(expert_w, wbf);
    gate_topk_kernel<<<N_TOK / 4, 256, 0, stream>>>(x, gate_w, gate_b, xbf,
                                                    counts, tok_list, gate_list);

    dim3 grid(N_TOK / TILE, HDIM / TILE, NE);   // 64 x 8 x 8, empty tiles early-exit
    moe_gemm_kernel<<<grid, 256, 0, stream>>>(xbf, wbf, expert_b,
                                              counts, tok_list, gate_list, out);
}

// Round 3
// 315.624 us; speedup vs baseline: 1.6122x; 1.6011x over previous
//
#include <hip/hip_runtime.h>
#include <hip/hip_bf16.h>
#include <math.h>

#define N_TOK 8192
#define HDIM  1024
#define NE    8
#define TILE  128
#define BK    64
#define NBLK  (N_TOK / 256)   // 32 histogram blocks

typedef __attribute__((ext_vector_type(8))) short bf16x8;
typedef __attribute__((ext_vector_type(4))) float f32x4;
typedef unsigned short u16;

__device__ __forceinline__ u16 f2bf(float f) {
    union { float f; unsigned u; } v; v.f = f;
    unsigned r = v.u + 0x7FFFu + ((v.u >> 16) & 1u);   // round-to-nearest-even
    return (u16)(r >> 16);
}

__device__ __forceinline__ void gld_lds16(const void* g, void* lds) {
    __builtin_amdgcn_global_load_lds(
        (const __attribute__((address_space(1))) unsigned int*)g,
        (__attribute__((address_space(3))) unsigned int*)lds,
        16, 0, 0);
}

// ---------------- expert_w fp32 -> bf16 ----------------
__global__ __launch_bounds__(256)
void convert_w_kernel(const float* __restrict__ w, u16* __restrict__ wbf) {
    size_t i = (size_t)blockIdx.x * 256 + threadIdx.x;
    float4 v = ((const float4*)w)[i];
    ushort4 b;
    b.x = f2bf(v.x); b.y = f2bf(v.y); b.z = f2bf(v.z); b.w = f2bf(v.w);
    ((ushort4*)wbf)[i] = b;
}

// ---- gating (wave per token): logits, softmax, top-2 -> per-token records; x -> bf16 ----
__global__ __launch_bounds__(256)
void gate_topk_kernel(const float* __restrict__ x,
                      const float* __restrict__ gate_w,
                      const float* __restrict__ gate_b,
                      u16* __restrict__ xbf,
                      int* __restrict__ eids,      // [N_TOK] e0 | e1<<8
                      float2* __restrict__ gatesv) // [N_TOK] (g0,g1)
{
    int wave = threadIdx.x >> 6, lane = threadIdx.x & 63;
    int t = blockIdx.x * 4 + wave;
    const float4* xt = (const float4*)(x + (size_t)t * HDIM);
    ushort4* xb = (ushort4*)(xbf + (size_t)t * HDIM);

    float acc[NE];
#pragma unroll
    for (int e = 0; e < NE; ++e) acc[e] = 0.f;

#pragma unroll
    for (int i = 0; i < 4; ++i) {
        int f = i * 64 + lane;
        float4 v = xt[f];
        ushort4 b;
        b.x = f2bf(v.x); b.y = f2bf(v.y); b.z = f2bf(v.z); b.w = f2bf(v.w);
        xb[f] = b;
#pragma unroll
        for (int e = 0; e < NE; ++e) {
            float4 wv = ((const float4*)(gate_w + e * HDIM))[f];
            acc[e] += v.x * wv.x + v.y * wv.y + v.z * wv.z + v.w * wv.w;
        }
    }
#pragma unroll
    for (int e = 0; e < NE; ++e)
        for (int off = 32; off > 0; off >>= 1)
            acc[e] += __shfl_down(acc[e], off);

    if (lane == 0) {
        float logit[NE];
        float mx = -1e30f;
#pragma unroll
        for (int e = 0; e < NE; ++e) {
            logit[e] = acc[e] + gate_b[e];
            mx = fmaxf(mx, logit[e]);
        }
        float p[NE], s = 0.f;
#pragma unroll
        for (int e = 0; e < NE; ++e) { p[e] = expf(logit[e] - mx); s += p[e]; }
        float inv = 1.f / s;
        int i0 = 0;
#pragma unroll
        for (int e = 1; e < NE; ++e) if (logit[e] > logit[i0]) i0 = e;
        int i1 = (i0 == 0) ? 1 : 0;
#pragma unroll
        for (int e = 0; e < NE; ++e) if (e != i0 && logit[e] > logit[i1]) i1 = e;

        eids[t]   = i0 | (i1 << 8);
        gatesv[t] = make_float2(p[i0] * inv, p[i1] * inv);
    }
}

// ---- per-block histogram + within-block rank (LDS atomics only) ----
__global__ __launch_bounds__(256)
void histrank_kernel(const int* __restrict__ eids,
                     int* __restrict__ ranks, int* __restrict__ hist) {
    __shared__ int lh[NE];
    int b = blockIdx.x, tid = threadIdx.x;
    if (tid < NE) lh[tid] = 0;
    __syncthreads();
    int t = b * 256 + tid;
    int ee = eids[t];
    int e0 = ee & 255, e1 = (ee >> 8) & 255;
    int r0 = atomicAdd(&lh[e0], 1);
    int r1 = atomicAdd(&lh[e1], 1);
    ranks[t] = r0 | (r1 << 16);
    __syncthreads();
    if (tid < NE) hist[b * NE + tid] = lh[tid];
}

// ---- tiny scan: per-expert block bases + totals ----
__global__ void scan_kernel(const int* __restrict__ hist,
                            int* __restrict__ base, int* __restrict__ counts) {
    int e = threadIdx.x;
    if (e < NE) {
        int run = 0;
        for (int b = 0; b < NBLK; ++b) { base[b * NE + e] = run; run += hist[b * NE + e]; }
        counts[e] = run;
    }
}

// ---- deterministic scatter into compact per-expert lists (no atomics) ----
__global__ __launch_bounds__(256)
void scatter_kernel(const int* __restrict__ eids, const int* __restrict__ ranks,
                    const float2* __restrict__ gatesv, const int* __restrict__ base,
                    int* __restrict__ tok_list, float* __restrict__ gate_list) {
    int b = blockIdx.x, tid = threadIdx.x;
    int t = b * 256 + tid;
    int ee = eids[t]; int e0 = ee & 255, e1 = (ee >> 8) & 255;
    int rk = ranks[t]; int r0 = rk & 0xffff, r1 = rk >> 16;
    float2 g = gatesv[t];
    int p0 = base[b * NE + e0] + r0;
    tok_list[e0 * N_TOK + p0]  = t * 2;          // token*2 + slot
    gate_list[e0 * N_TOK + p0] = g.x;
    int p1 = base[b * NE + e1] + r1;
    tok_list[e1 * N_TOK + p1]  = t * 2 + 1;
    gate_list[e1 * N_TOK + p1] = g.y;
}

// ---- grouped per-expert GEMM (bf16, async LDS staging, BK=64, plain stores) ----
// LDS chunk-major [8][128] 16B slots: global_load_lds wave-uniform rule + conflict-free b128 reads.
__global__ __launch_bounds__(256)
void moe_gemm_kernel(const u16* __restrict__ xbf,
                     const u16* __restrict__ wbf,
                     const float* __restrict__ expert_b,
                     const int* __restrict__ counts,
                     const int* __restrict__ tok_list,
                     const float* __restrict__ gate_list,
                     float* __restrict__ out,      // slot0 partials
                     float* __restrict__ part1)    // slot1 partials
{
    int e   = blockIdx.z;
    int cnt = counts[e];
    int m0  = blockIdx.x * TILE;
    if (m0 >= cnt) return;
    int n0  = blockIdx.y * TILE;

    __shared__ __align__(16) u16 As[8 * 128 * 8];   // 16 KB
    __shared__ __align__(16) u16 Bs[8 * 128 * 8];   // 16 KB

    int tid = threadIdx.x;
    int w = tid >> 6, l = tid & 63;
    int r  = ((w & 1) << 6) + l;      // staged row (same row all 4 instrs)
    int c0 = w >> 1;                  // chunk base; instr j adds 2j

    int tr = m0 + r; if (tr > cnt - 1) tr = cnt - 1;   // dup rows discarded in epilogue
    int lstA = tok_list[e * N_TOK + tr];
    const u16* aptr = xbf + (size_t)(lstA >> 1) * HDIM + c0 * 8;
    const u16* bptr = wbf + (size_t)(e * HDIM + n0 + r) * HDIM + c0 * 8;

    int wm = (w >> 1) * 64, wn = (w & 1) * 64;
    int lrow = l & 15, quad = l >> 4;

    f32x4 acc[4][4];
#pragma unroll
    for (int mi = 0; mi < 4; ++mi)
#pragma unroll
        for (int ni = 0; ni < 4; ++ni)
            acc[mi][ni] = (f32x4){0.f, 0.f, 0.f, 0.f};

    for (int k0 = 0; k0 < HDIM; k0 += BK) {
#pragma unroll
        for (int j = 0; j < 4; ++j) {
            gld_lds16(aptr + k0 + j * 16, As + (w * 64 + j * 256) * 8);
            gld_lds16(bptr + k0 + j * 16, Bs + (w * 64 + j * 256) * 8);
        }
        __syncthreads();

#pragma unroll
        for (int t2 = 0; t2 < 2; ++t2) {
            bf16x8 af[4], bfr[4];
#pragma unroll
            for (int i = 0; i < 4; ++i) {
                af[i]  = *(const bf16x8*)(As + ((t2 * 4 + quad) * 128 + wm + i * 16 + lrow) * 8);
                bfr[i] = *(const bf16x8*)(Bs + ((t2 * 4 + quad) * 128 + wn + i * 16 + lrow) * 8);
            }
#pragma unroll
            for (int mi = 0; mi < 4; ++mi)
#pragma unroll
                for (int ni = 0; ni < 4; ++ni)
                    acc[mi][ni] = __builtin_amdgcn_mfma_f32_16x16x32_bf16(
                        af[mi], bfr[ni], acc[mi][ni], 0, 0, 0);
        }
        __syncthreads();
    }

    // epilogue: bias + gate, PLAIN stores to (token,slot) partial rows
#pragma unroll
    for (int mi = 0; mi < 4; ++mi) {
#pragma unroll
        for (int rr = 0; rr < 4; ++rr) {
            int listRow = m0 + wm + mi * 16 + quad * 4 + rr;
            if (listRow < cnt) {
                int   lst = tok_list[e * N_TOK + listRow];
                float g   = gate_list[e * N_TOK + listRow];
                float* dst = ((lst & 1) ? part1 : out) + (size_t)(lst >> 1) * HDIM;
#pragma unroll
                for (int ni = 0; ni < 4; ++ni) {
                    int col = n0 + wn + ni * 16 + lrow;
                    dst[col] = (acc[mi][ni][rr] + expert_b[e * HDIM + col]) * g;
                }
            }
        }
    }
}

// ---- combine: out += part1 ----
__global__ __launch_bounds__(256)
void combine_kernel(float* __restrict__ out, const float* __restrict__ part1) {
    size_t i = (size_t)blockIdx.x * 256 + threadIdx.x;
    float4 a = ((const float4*)out)[i];
    float4 b = ((const float4*)part1)[i];
    a.x += b.x; a.y += b.y; a.z += b.z; a.w += b.w;
    ((float4*)out)[i] = a;
}

extern "C" void kernel_launch(void* const* d_in, const int* in_sizes, int n_in,
                              void* d_out, int out_size, void* d_ws, size_t ws_size,
                              hipStream_t stream)
{
    const float* x        = (const float*)d_in[0];
    const float* gate_w   = (const float*)d_in[1];
    const float* gate_b   = (const float*)d_in[2];
    const float* expert_w = (const float*)d_in[3];
    const float* expert_b = (const float*)d_in[4];
    float* out = (float*)d_out;

    char* ws = (char*)d_ws;
    int*    eids      = (int*)(ws);                         // 32 KB
    int*    ranks     = (int*)(ws + (32 << 10));            // 32 KB
    float2* gatesv    = (float2*)(ws + (64 << 10));         // 64 KB
    int*    hist      = (int*)(ws + (128 << 10));           // 1 KB
    int*    base      = (int*)(ws + (130 << 10));           // 1 KB
    int*    counts    = (int*)(ws + (132 << 10));           // 256 B
    int*    tok_list  = (int*)(ws + (136 << 10));           // 256 KB
    float*  gate_list = (float*)(ws + (136 << 10) + NE * N_TOK * 4); // 256 KB
    u16*    xbf       = (u16*)(ws + (1 << 20));             // 16 MB
    u16*    wbf       = xbf + (size_t)N_TOK * HDIM;         // 16 MB
    float*  part1     = (float*)(ws + (33u << 20));         // 32 MB

    convert_w_kernel<<<(NE * HDIM * HDIM / 4) / 256, 256, 0, stream>>>(expert_w, wbf);
    gate_topk_kernel<<<N_TOK / 4, 256, 0, stream>>>(x, gate_w, gate_b, xbf,
                                                    eids, gatesv);
    histrank_kernel<<<NBLK, 256, 0, stream>>>(eids, ranks, hist);
    scan_kernel<<<1, 64, 0, stream>>>(hist, base, counts);
    scatter_kernel<<<NBLK, 256, 0, stream>>>(eids, ranks, gatesv, base,
                                             tok_list, gate_list);

    dim3 grid(N_TOK / TILE, HDIM / TILE, NE);   // empty tiles early-exit
    moe_gemm_kernel<<<grid, 256, 0, stream>>>(xbf, wbf, expert_b,
                                              counts, tok_list, gate_list, out, part1);

    combine_kernel<<<N_TOK * HDIM / 4 / 256, 256, 0, stream>>>(out, part1);
}

// Round 4
// 243.977 us; speedup vs baseline: 2.0857x; 1.2937x over previous
//
#include <hip/hip_runtime.h>
#include <hip/hip_bf16.h>
#include <math.h>

#define N_TOK 8192
#define HDIM  1024
#define NE    8
#define TILE  128
#define BK    64
#define NCONV 8192                 // convert_w blocks
#define NGATE (N_TOK / 4)          // gate blocks (4 tokens each)

typedef __attribute__((ext_vector_type(8))) short bf16x8;
typedef __attribute__((ext_vector_type(4))) float f32x4;
typedef unsigned short u16;

__device__ __forceinline__ u16 f2bf(float f) {
    union { float f; unsigned u; } v; v.f = f;
    unsigned r = v.u + 0x7FFFu + ((v.u >> 16) & 1u);   // round-to-nearest-even
    return (u16)(r >> 16);
}

__device__ __forceinline__ void gld_lds16(const void* g, void* lds) {
    __builtin_amdgcn_global_load_lds(
        (const __attribute__((address_space(1))) unsigned int*)g,
        (__attribute__((address_space(3))) unsigned int*)lds,
        16, 0, 0);
}

// ---- prep: blocks [0,NCONV) convert expert_w fp32->bf16; blocks [NCONV,..) gate+x->bf16 ----
__global__ __launch_bounds__(256)
void prep_kernel(const float* __restrict__ w, u16* __restrict__ wbf,
                 const float* __restrict__ x,
                 const float* __restrict__ gate_w,
                 const float* __restrict__ gate_b,
                 u16* __restrict__ xbf,
                 int* __restrict__ eids,       // [N_TOK] e0 | e1<<8
                 float2* __restrict__ gatesv)  // [N_TOK] (g0,g1)
{
    int bid = blockIdx.x;
    if (bid < NCONV) {
        size_t i = (size_t)bid * 256 + threadIdx.x;   // float4 index
        float4 v = ((const float4*)w)[i];
        ushort4 b;
        b.x = f2bf(v.x); b.y = f2bf(v.y); b.z = f2bf(v.z); b.w = f2bf(v.w);
        ((ushort4*)wbf)[i] = b;
        return;
    }
    int gb = bid - NCONV;
    int wave = threadIdx.x >> 6, lane = threadIdx.x & 63;
    int t = gb * 4 + wave;
    const float4* xt = (const float4*)(x + (size_t)t * HDIM);
    ushort4* xb = (ushort4*)(xbf + (size_t)t * HDIM);

    float acc[NE];
#pragma unroll
    for (int e = 0; e < NE; ++e) acc[e] = 0.f;

#pragma unroll
    for (int i = 0; i < 4; ++i) {
        int f = i * 64 + lane;
        float4 v = xt[f];
        ushort4 b;
        b.x = f2bf(v.x); b.y = f2bf(v.y); b.z = f2bf(v.z); b.w = f2bf(v.w);
        xb[f] = b;
#pragma unroll
        for (int e = 0; e < NE; ++e) {
            float4 wv = ((const float4*)(gate_w + e * HDIM))[f];
            acc[e] += v.x * wv.x + v.y * wv.y + v.z * wv.z + v.w * wv.w;
        }
    }
#pragma unroll
    for (int e = 0; e < NE; ++e)
        for (int off = 32; off > 0; off >>= 1)
            acc[e] += __shfl_down(acc[e], off);

    if (lane == 0) {
        float logit[NE];
        float mx = -1e30f;
#pragma unroll
        for (int e = 0; e < NE; ++e) {
            logit[e] = acc[e] + gate_b[e];
            mx = fmaxf(mx, logit[e]);
        }
        float p[NE], s = 0.f;
#pragma unroll
        for (int e = 0; e < NE; ++e) { p[e] = expf(logit[e] - mx); s += p[e]; }
        float inv = 1.f / s;
        int i0 = 0;
#pragma unroll
        for (int e = 1; e < NE; ++e) if (logit[e] > logit[i0]) i0 = e;
        int i1 = (i0 == 0) ? 1 : 0;
#pragma unroll
        for (int e = 0; e < NE; ++e) if (e != i0 && logit[e] > logit[i1]) i1 = e;

        eids[t]   = i0 | (i1 << 8);
        gatesv[t] = make_float2(p[i0] * inv, p[i1] * inv);
    }
}

// ---- compact: single block, hist+rank+scatter (16 sub-histograms to cut contention) ----
__global__ __launch_bounds__(1024)
void compact_kernel(const int* __restrict__ eids,
                    const float2* __restrict__ gatesv,
                    int* __restrict__ tok_list, float* __restrict__ gate_list,
                    int* __restrict__ counts)
{
    __shared__ int lh[16][NE];
    __shared__ int lbase[16][NE];
    int tid = threadIdx.x;
    if (tid < 16 * NE) ((int*)lh)[tid] = 0;
    __syncthreads();
    int bucket = tid & 15;

    int e0v[8], e1v[8], r0v[8], r1v[8];
    float2 gv[8];
#pragma unroll
    for (int it = 0; it < 8; ++it) {
        int t = it * 1024 + tid;
        int ee = eids[t];
        e0v[it] = ee & 255; e1v[it] = (ee >> 8) & 255;
        gv[it] = gatesv[t];
        r0v[it] = atomicAdd(&lh[bucket][e0v[it]], 1);
        r1v[it] = atomicAdd(&lh[bucket][e1v[it]], 1);
    }
    __syncthreads();
    if (tid < NE) {
        int run = 0;
        for (int b = 0; b < 16; ++b) { lbase[b][tid] = run; run += lh[b][tid]; }
        counts[tid] = run;
    }
    __syncthreads();
#pragma unroll
    for (int it = 0; it < 8; ++it) {
        int t = it * 1024 + tid;
        int p0 = lbase[bucket][e0v[it]] + r0v[it];
        tok_list[e0v[it] * N_TOK + p0]  = t * 2;        // token*2 + slot
        gate_list[e0v[it] * N_TOK + p0] = gv[it].x;
        int p1 = lbase[bucket][e1v[it]] + r1v[it];
        tok_list[e1v[it] * N_TOK + p1]  = t * 2 + 1;
        gate_list[e1v[it] * N_TOK + p1] = gv[it].y;
    }
}

// ---- grouped per-expert GEMM: coalesced XOR-swizzled async staging, plain stores ----
// LDS: 1024 slots of 16B per matrix. Slot s holds (row = s>>3, chunk = (s&7)^(row&7)).
// Staging: lane reads 16B at global chunk csrc=(s&7)^(row&7) -> 8 lanes/row, contiguous 128B.
// Fragment read row r chunk c -> slot r*8 + (c^(r&7)): banks (c^(r&7))*4 -> conflict-free.
__global__ __launch_bounds__(256)
void moe_gemm_kernel(const u16* __restrict__ xbf,
                     const u16* __restrict__ wbf,
                     const float* __restrict__ expert_b,
                     const int* __restrict__ counts,
                     const int* __restrict__ tok_list,
                     const float* __restrict__ gate_list,
                     float* __restrict__ out,      // slot0 partials
                     float* __restrict__ part1)    // slot1 partials
{
    int e   = blockIdx.z;
    int cnt = counts[e];
    int m0  = blockIdx.x * TILE;
    if (m0 >= cnt) return;
    int n0  = blockIdx.y * TILE;

    __shared__ __align__(16) u16 As[1024 * 8];   // 16 KB
    __shared__ __align__(16) u16 Bs[1024 * 8];   // 16 KB

    int tid = threadIdx.x;
    int w = tid >> 6, l = tid & 63;

    const u16* aP[4];
    const u16* bP[4];
#pragma unroll
    for (int j = 0; j < 4; ++j) {
        int s = j * 256 + w * 64 + l;
        int r = s >> 3;
        int cs = (s & 7) ^ (r & 7);
        int tr = m0 + r; if (tr > cnt - 1) tr = cnt - 1;   // dup rows discarded in epilogue
        int lst = tok_list[e * N_TOK + tr];
        aP[j] = xbf + (size_t)(lst >> 1) * HDIM + cs * 8;
        bP[j] = wbf + (size_t)(e * HDIM + n0 + r) * HDIM + cs * 8;
    }

    int wm = (w >> 1) * 64, wn = (w & 1) * 64;
    int lrow = l & 15, quad = l >> 4;
    int cxbase = lrow & 7;           // row&7 for all fragment rows this lane touches

    f32x4 acc[4][4];
#pragma unroll
    for (int mi = 0; mi < 4; ++mi)
#pragma unroll
        for (int ni = 0; ni < 4; ++ni)
            acc[mi][ni] = (f32x4){0.f, 0.f, 0.f, 0.f};

    for (int k0 = 0; k0 < HDIM; k0 += BK) {
#pragma unroll
        for (int j = 0; j < 4; ++j) {
            gld_lds16(aP[j] + k0, As + (j * 256 + w * 64) * 8);
            gld_lds16(bP[j] + k0, Bs + (j * 256 + w * 64) * 8);
        }
        __syncthreads();

#pragma unroll
        for (int t2 = 0; t2 < 2; ++t2) {
            int cx = (t2 * 4 + quad) ^ cxbase;   // swizzled chunk for this lane
            bf16x8 af[4], bfr[4];
#pragma unroll
            for (int i = 0; i < 4; ++i) {
                int ra = wm + i * 16 + lrow;
                int rb = wn + i * 16 + lrow;
                af[i]  = *(const bf16x8*)(As + (ra * 8 + cx) * 8);
                bfr[i] = *(const bf16x8*)(Bs + (rb * 8 + cx) * 8);
            }
#pragma unroll
            for (int mi = 0; mi < 4; ++mi)
#pragma unroll
                for (int ni = 0; ni < 4; ++ni)
                    acc[mi][ni] = __builtin_amdgcn_mfma_f32_16x16x32_bf16(
                        af[mi], bfr[ni], acc[mi][ni], 0, 0, 0);
        }
        __syncthreads();
    }

    // epilogue: bias + gate, plain stores to (token,slot) partial rows
#pragma unroll
    for (int mi = 0; mi < 4; ++mi) {
#pragma unroll
        for (int rr = 0; rr < 4; ++rr) {
            int listRow = m0 + wm + mi * 16 + quad * 4 + rr;
            if (listRow < cnt) {
                int   lst = tok_list[e * N_TOK + listRow];
                float g   = gate_list[e * N_TOK + listRow];
                float* dst = ((lst & 1) ? part1 : out) + (size_t)(lst >> 1) * HDIM;
#pragma unroll
                for (int ni = 0; ni < 4; ++ni) {
                    int col = n0 + wn + ni * 16 + lrow;
                    dst[col] = (acc[mi][ni][rr] + expert_b[e * HDIM + col]) * g;
                }
            }
        }
    }
}

// ---- combine: out += part1 ----
__global__ __launch_bounds__(256)
void combine_kernel(float* __restrict__ out, const float* __restrict__ part1) {
    size_t i = (size_t)blockIdx.x * 256 + threadIdx.x;
    float4 a = ((const float4*)out)[i];
    float4 b = ((const float4*)part1)[i];
    a.x += b.x; a.y += b.y; a.z += b.z; a.w += b.w;
    ((float4*)out)[i] = a;
}

extern "C" void kernel_launch(void* const* d_in, const int* in_sizes, int n_in,
                              void* d_out, int out_size, void* d_ws, size_t ws_size,
                              hipStream_t stream)
{
    const float* x        = (const float*)d_in[0];
    const float* gate_w   = (const float*)d_in[1];
    const float* gate_b   = (const float*)d_in[2];
    const float* expert_w = (const float*)d_in[3];
    const float* expert_b = (const float*)d_in[4];
    float* out = (float*)d_out;

    char* ws = (char*)d_ws;
    int*    eids      = (int*)(ws);                         // 32 KB
    float2* gatesv    = (float2*)(ws + (64 << 10));         // 64 KB
    int*    counts    = (int*)(ws + (132 << 10));           // 256 B
    int*    tok_list  = (int*)(ws + (136 << 10));           // 256 KB
    float*  gate_list = (float*)(ws + (136 << 10) + NE * N_TOK * 4); // 256 KB
    u16*    xbf       = (u16*)(ws + (1 << 20));             // 16 MB
    u16*    wbf       = xbf + (size_t)N_TOK * HDIM;         // 16 MB
    float*  part1     = (float*)(ws + (33u << 20));         // 32 MB

    prep_kernel<<<NCONV + NGATE, 256, 0, stream>>>(expert_w, wbf, x, gate_w, gate_b,
                                                   xbf, eids, gatesv);
    compact_kernel<<<1, 1024, 0, stream>>>(eids, gatesv, tok_list, gate_list, counts);

    dim3 grid(N_TOK / TILE, HDIM / TILE, NE);   // empty tiles early-exit
    moe_gemm_kernel<<<grid, 256, 0, stream>>>(xbf, wbf, expert_b,
                                              counts, tok_list, gate_list, out, part1);

    combine_kernel<<<N_TOK * HDIM / 4 / 256, 256, 0, stream>>>(out, part1);
}